// Round 6
// baseline (236.520 us; speedup 1.0000x reference)
//
#include <hip/hip_runtime.h>
#include <stdint.h>

#define B_    8
#define DK_   128
#define DV_   512
#define M_    3136      // H*W
#define N_    6272      // T*H*W
#define MT128_ 25       // ceil(3136/128)
#define NSEG_ 16
#define NTILES_ 98      // N_/64 dense
#define TH_   30.0f
#define MARGIN_ 36.0f
#define BKT_  128

typedef short bf16x8 __attribute__((ext_vector_type(8)));
typedef float f32x16 __attribute__((ext_vector_type(16)));
typedef unsigned short u16x8 __attribute__((ext_vector_type(8)));

__device__ __forceinline__ unsigned short f2bf(float x) {
  unsigned u = __float_as_uint(x);
  return (unsigned short)((u + 0x7fffu + ((u >> 16) & 1u)) >> 16);
}
__device__ __forceinline__ float bf2f(unsigned short h) {
  return __uint_as_float(((unsigned)h) << 16);
}

// ---- fused prep: vectorized transposes + q-scan + bcnt zero + mask bitwords ----
// grid: [0,784) qkeyT; [784,2352) mkeyT+mkb; [2352,8624) mvalT;
//       [8624,8632) q scan; [8632,8657) zero bcnt; [8657,8665) mmbits
__global__ __launch_bounds__(256)
void prep_kernel(const float* __restrict__ qkey, const int* __restrict__ qmask,
                 const float* __restrict__ mkey, const float* __restrict__ mval,
                 const int* __restrict__ mmask,
                 float* __restrict__ qkeyT, float* __restrict__ mkeyT,
                 unsigned short* __restrict__ mkb, unsigned short* __restrict__ mvalT,
                 int* __restrict__ qlist, int* __restrict__ qcnt,
                 unsigned* __restrict__ bcnt_z, unsigned long long* __restrict__ mmbits) {
  __shared__ float T[64][65];
  int r = blockIdx.x;
  int tid = threadIdx.x;
  int r16 = tid >> 4, c4 = (tid & 15) << 2;
  if (r < 784) {                       // qkey [B][128][M] -> fp32 [B][M][128], x40
    int xt = r % 49, dt = (r / 49) & 1, b = r / 98;
    const float* src = qkey + ((size_t)b * DK_ + dt * 64) * M_ + xt * 64;
    #pragma unroll
    for (int i = 0; i < 4; ++i) {
      int row = i * 16 + r16;
      float4 v = *(const float4*)&src[(size_t)row * M_ + c4];
      T[row][c4] = v.x; T[row][c4 + 1] = v.y; T[row][c4 + 2] = v.z; T[row][c4 + 3] = v.w;
    }
    __syncthreads();
    #pragma unroll
    for (int i = 0; i < 4; ++i) {
      int xl = i * 16 + r16;
      float4 v = make_float4(40.f * T[c4][xl], 40.f * T[c4 + 1][xl],
                             40.f * T[c4 + 2][xl], 40.f * T[c4 + 3][xl]);
      *(float4*)&qkeyT[((size_t)b * M_ + xt * 64 + xl) * DK_ + dt * 64 + c4] = v;
    }
  } else if (r < 2352) {               // mkey -> fp32 T + bf16 T
    int r2 = r - 784;
    int xt = r2 % 98, dt = (r2 / 98) & 1, b = r2 / 196;
    const float* src = mkey + ((size_t)b * DK_ + dt * 64) * N_ + xt * 64;
    #pragma unroll
    for (int i = 0; i < 4; ++i) {
      int row = i * 16 + r16;
      float4 v = *(const float4*)&src[(size_t)row * N_ + c4];
      T[row][c4] = v.x; T[row][c4 + 1] = v.y; T[row][c4 + 2] = v.z; T[row][c4 + 3] = v.w;
    }
    __syncthreads();
    #pragma unroll
    for (int i = 0; i < 4; ++i) {
      int xl = i * 16 + r16;
      float4 v = make_float4(T[c4][xl], T[c4 + 1][xl], T[c4 + 2][xl], T[c4 + 3][xl]);
      size_t idx = ((size_t)b * N_ + xt * 64 + xl) * DK_ + dt * 64 + c4;
      *(float4*)&mkeyT[idx] = v;
      ushort4 h;
      h.x = f2bf(v.x); h.y = f2bf(v.y); h.z = f2bf(v.z); h.w = f2bf(v.w);
      *(ushort4*)&mkb[idx] = h;
    }
  } else if (r < 8624) {               // mval -> bf16 [B][N][512]
    int r3 = r - 2352;
    int nt = r3 % 98, dvt = (r3 / 98) & 7, b = r3 / 784;
    const float* src = mval + ((size_t)b * DV_ + dvt * 64) * N_ + nt * 64;
    #pragma unroll
    for (int i = 0; i < 4; ++i) {
      int row = i * 16 + r16;
      float4 v = *(const float4*)&src[(size_t)row * N_ + c4];
      T[row][c4] = v.x; T[row][c4 + 1] = v.y; T[row][c4 + 2] = v.z; T[row][c4 + 3] = v.w;
    }
    __syncthreads();
    #pragma unroll
    for (int i = 0; i < 4; ++i) {
      int xl = i * 16 + r16;
      ushort4 h;
      h.x = f2bf(T[c4][xl]); h.y = f2bf(T[c4 + 1][xl]);
      h.z = f2bf(T[c4 + 2][xl]); h.w = f2bf(T[c4 + 3][xl]);
      *(ushort4*)&mvalT[((size_t)b * N_ + nt * 64 + xl) * DV_ + dvt * 64 + c4] = h;
    }
  } else if (r < 8632) {               // q-mask compaction
    int b = r - 8624;
    __shared__ int wsum[4];
    __shared__ int cbase;
    int lane = tid & 63, wv = tid >> 6;
    if (tid == 0) cbase = 0;
    __syncthreads();
    for (int base = 0; base < M_; base += 256) {
      int i = base + tid;
      int flag = (i < M_) ? (qmask[b * M_ + i] != 0) : 0;
      unsigned long long bal = __ballot(flag);
      int prefix = __popcll(bal & ((1ull << lane) - 1ull));
      if (lane == 0) wsum[wv] = __popcll(bal);
      __syncthreads();
      int woff = 0;
      for (int t = 0; t < wv; ++t) woff += wsum[t];
      int total = wsum[0] + wsum[1] + wsum[2] + wsum[3];
      if (flag) qlist[b * M_ + cbase + woff + prefix] = i;
      __syncthreads();
      if (tid == 0) cbase += total;
      __syncthreads();
    }
    if (tid == 0) qcnt[b] = cbase;
  } else if (r < 8657) {               // zero bcnt (padded region 25*4096B)
    unsigned* p = bcnt_z + (size_t)(r - 8632) * 1024;
    for (int i = tid; i < 1024; i += 256) p[i] = 0u;
  } else {                             // mmask -> per-tile 64-bit words
    int b = r - 8657;
    int lane = tid & 63, wv = tid >> 6;
    for (int t = wv; t < NTILES_; t += 4) {
      unsigned long long word = __ballot(mmask[b * N_ + t * 64 + lane] != 0);
      if (lane == 0) mmbits[b * NTILES_ + t] = word;
    }
  }
}

// ---- bf16-MFMA score: dense n, Q regs, gload_lds dbuf, block-local max only ----
__global__ __launch_bounds__(256, 4)
void score_mfma(const float* __restrict__ qkeyT, const unsigned short* __restrict__ mkb,
                const int* __restrict__ qlist, const int* __restrict__ qcnt,
                const unsigned long long* __restrict__ mmbits,
                unsigned* __restrict__ bcnt, unsigned* __restrict__ bucket) {
  int bid = blockIdx.x;
  int seg = bid & (NSEG_ - 1);
  int t   = bid >> 4;
  int mt  = t % MT128_;
  int b   = t / MT128_;
  int mc = qcnt[b];
  if (mt * 128 >= mc) return;
  int t0 = (NTILES_ * seg) / NSEG_;
  int t1 = (NTILES_ * (seg + 1)) / NSEG_;

  __shared__ unsigned short Ks[2][64 * 128];  // chunk-major: c*1024B + row*16B

  int tid = threadIdx.x;
  int lane = tid & 63, wv = tid >> 6;
  int l31 = lane & 31, lhi = lane >> 5;
  int mrow = wv * 32 + l31;

  // Q fragments: fp32 row (x40 prefolded) -> bf16 regs
  int cm = mt * 128 + mrow;
  int col = (cm < mc) ? qlist[b * M_ + cm] : qlist[b * M_];
  int mo  = (cm < mc) ? col : -1;
  const float* qrowf = qkeyT + ((size_t)b * M_ + col) * DK_ + lhi * 8;
  bf16x8 qf[8];
  #pragma unroll
  for (int kc = 0; kc < 8; ++kc) {
    float4 v0 = *(const float4*)&qrowf[kc * 16];
    float4 v1 = *(const float4*)&qrowf[kc * 16 + 4];
    bf16x8 q;
    q[0] = (short)f2bf(v0.x); q[1] = (short)f2bf(v0.y);
    q[2] = (short)f2bf(v0.z); q[3] = (short)f2bf(v0.w);
    q[4] = (short)f2bf(v1.x); q[5] = (short)f2bf(v1.y);
    q[6] = (short)f2bf(v1.z); q[7] = (short)f2bf(v1.w);
    qf[kc] = q;
  }

  const unsigned short* mkb_b = mkb + (size_t)b * N_ * DK_;
  const unsigned long long* bits_b = mmbits + b * NTILES_;

  // prologue: stage tile t0 into buf 0
  {
    int nbase = t0 << 6;
    char* kd = (char*)&Ks[0][0];
    #pragma unroll
    for (int i = 0; i < 4; ++i) {
      int c = wv * 4 + i;
      const unsigned short* src = mkb_b + ((size_t)(nbase + lane)) * DK_ + c * 8;
      __builtin_amdgcn_global_load_lds(
          (const __attribute__((address_space(1))) unsigned*)src,
          (__attribute__((address_space(3))) unsigned*)(kd + c * 1024), 16, 0, 0);
    }
  }
  asm volatile("s_waitcnt vmcnt(0)" ::: "memory");
  __syncthreads();

  float runmax = -3.0e38f;

  for (int tt = t0; tt < t1; ++tt) {
    int cur = (tt - t0) & 1;
    int nbase = tt << 6;
    // prefetch next tile (hides under MFMA + epilogue)
    if (tt + 1 < t1) {
      int nb2 = (tt + 1) << 6;
      char* kd = (char*)&Ks[cur ^ 1][0];
      #pragma unroll
      for (int i = 0; i < 4; ++i) {
        int c = wv * 4 + i;
        const unsigned short* src = mkb_b + ((size_t)(nb2 + lane)) * DK_ + c * 8;
        __builtin_amdgcn_global_load_lds(
            (const __attribute__((address_space(1))) unsigned*)src,
            (__attribute__((address_space(3))) unsigned*)(kd + c * 1024), 16, 0, 0);
      }
    }
    unsigned long long bits = bits_b[tt];   // uniform scalar load

    const char* kb = (const char*)&Ks[cur][0];
    f32x16 acc0, acc1;
    #pragma unroll
    for (int r = 0; r < 16; ++r) { acc0[r] = 0.f; acc1[r] = 0.f; }
    #pragma unroll
    for (int kc = 0; kc < 8; ++kc) {
      int c = kc * 2 + lhi;
      bf16x8 a0 = *(const bf16x8*)(kb + c * 1024 + l31 * 16);
      bf16x8 a1 = *(const bf16x8*)(kb + c * 1024 + (32 + l31) * 16);
      acc0 = __builtin_amdgcn_mfma_f32_32x32x16_bf16(a0, qf[kc], acc0, 0, 0, 0);
      acc1 = __builtin_amdgcn_mfma_f32_32x32x16_bf16(a1, qf[kc], acc1, 0, 0, 0);
    }

    // masked running column max (block-local; true argmax always self-appends)
    unsigned long long b0 = bits >> (lhi << 2);
    unsigned long long b1 = (bits >> 32) >> (lhi << 2);
    float cmx = -3.0e38f;
    #pragma unroll
    for (int r = 0; r < 16; ++r) {
      const int pos = (r & 3) + ((r >> 2) << 3);
      if ((b0 >> pos) & 1) cmx = fmaxf(cmx, acc0[r]);
      if ((b1 >> pos) & 1) cmx = fmaxf(cmx, acc1[r]);
    }
    cmx = fmaxf(cmx, __shfl_xor(cmx, 32));
    runmax = fmaxf(runmax, cmx);

    // candidate appends: superset of {s_true >= max_true - TH}
    if (mo >= 0) {
      float thr = runmax - MARGIN_;
      #pragma unroll
      for (int r = 0; r < 16; ++r) {
        const int pos = (r & 3) + ((r >> 2) << 3);
        if (((b0 >> pos) & 1) && acc0[r] >= thr) {
          unsigned slot = atomicAdd(&bcnt[b * M_ + mo], 1u);
          if (slot < (unsigned)BKT_)
            bucket[(size_t)(b * M_ + mo) * BKT_ + slot] =
                (unsigned)(nbase + pos + (lhi << 2));
        }
        if (((b1 >> pos) & 1) && acc1[r] >= thr) {
          unsigned slot = atomicAdd(&bcnt[b * M_ + mo], 1u);
          if (slot < (unsigned)BKT_)
            bucket[(size_t)(b * M_ + mo) * BKT_ + slot] =
                (unsigned)(nbase + 32 + pos + (lhi << 2));
        }
      }
    }

    asm volatile("s_waitcnt vmcnt(0)" ::: "memory");
    __syncthreads();
  }
}

__device__ __forceinline__ float dot128(const float* __restrict__ q,
                                        const float* __restrict__ k) {
  float s = 0.f;
  #pragma unroll 8
  for (int i = 0; i < DK_; i += 4) {
    float4 a = *(const float4*)&q[i];
    float4 bb = *(const float4*)&k[i];
    s += a.x * bb.x + a.y * bb.y + a.z * bb.z + a.w * bb.w;
  }
  return s;
}

// ---- PV: one wave per active column; exact fp32 rescore of <=128 candidates ----
__global__ __launch_bounds__(256)
void pv_exact(const float* __restrict__ qkeyT, const float* __restrict__ mkeyT,
              const unsigned short* __restrict__ mvalT,
              const int* __restrict__ qlist, const int* __restrict__ qcnt,
              const int* __restrict__ mmask,
              const unsigned* __restrict__ bcnt, const unsigned* __restrict__ bucket,
              unsigned short* __restrict__ outT) {
  int b = blockIdx.y;
  int wv = threadIdx.x >> 6, lane = threadIdx.x & 63;
  int c = blockIdx.x * 4 + wv;
  if (c >= qcnt[b]) return;
  int m = qlist[b * M_ + c];
  unsigned cnt = bcnt[b * M_ + m];
  const float* qrow = qkeyT + ((size_t)b * M_ + m) * DK_;
  float acc[8] = {0.f, 0.f, 0.f, 0.f, 0.f, 0.f, 0.f, 0.f};
  float lsum = 0.f;

  if (cnt <= (unsigned)BKT_) {
    size_t base = (size_t)(b * M_ + m) * BKT_;
    int n0 = (lane < (int)cnt) ? (int)bucket[base + lane] : -1;
    int n1 = (lane + 64 < (int)cnt) ? (int)bucket[base + 64 + lane] : -1;
    float s0 = (n0 >= 0) ? dot128(qrow, mkeyT + ((size_t)b * N_ + n0) * DK_) : -3.0e38f;
    float s1 = (n1 >= 0) ? dot128(qrow, mkeyT + ((size_t)b * N_ + n1) * DK_) : -3.0e38f;
    float mx = fmaxf(s0, s1);
    #pragma unroll
    for (int o = 32; o > 0; o >>= 1) mx = fmaxf(mx, __shfl_xor(mx, o));
    float e0 = (n0 >= 0 && s0 >= mx - TH_) ? expf(s0 - mx) : 0.f;
    float e1 = (n1 >= 0 && s1 >= mx - TH_) ? expf(s1 - mx) : 0.f;
    lsum = e0 + e1;
    #pragma unroll
    for (int o = 32; o > 0; o >>= 1) lsum += __shfl_xor(lsum, o);
    unsigned long long alive = __ballot(e0 > 0.f);
    while (alive) {
      int lb = __ffsll((unsigned long long)alive) - 1;
      alive &= alive - 1;
      float w = __shfl(e0, lb);
      int nn = __shfl(n0, lb);
      u16x8 vvv = *(const u16x8*)(mvalT + ((size_t)b * N_ + nn) * DV_ + lane * 8);
      #pragma unroll
      for (int r = 0; r < 8; ++r) acc[r] += w * bf2f(vvv[r]);
    }
    alive = __ballot(e1 > 0.f);
    while (alive) {
      int lb = __ffsll((unsigned long long)alive) - 1;
      alive &= alive - 1;
      float w = __shfl(e1, lb);
      int nn = __shfl(n1, lb);
      u16x8 vvv = *(const u16x8*)(mvalT + ((size_t)b * N_ + nn) * DV_ + lane * 8);
      #pragma unroll
      for (int r = 0; r < 8; ++r) acc[r] += w * bf2f(vvv[r]);
    }
  } else {
    // overflow fallback (statistically unreachable): exact dense two-pass
    float mx = -3.0e38f;
    for (int base = 0; base < N_; base += 64) {
      int n = base + lane;
      float sv = -3.0e38f;
      if (mmask[b * N_ + n] != 0)
        sv = dot128(qrow, mkeyT + ((size_t)b * N_ + n) * DK_);
      mx = fmaxf(mx, sv);
    }
    #pragma unroll
    for (int o = 32; o > 0; o >>= 1) mx = fmaxf(mx, __shfl_xor(mx, o));
    for (int base = 0; base < N_; base += 64) {
      int n = base + lane;
      bool act = (mmask[b * N_ + n] != 0);
      float sv = -3.0e38f;
      if (act) sv = dot128(qrow, mkeyT + ((size_t)b * N_ + n) * DK_);
      float e = (act && sv >= mx - TH_) ? expf(sv - mx) : 0.f;
      lsum += e;
      unsigned long long alive = __ballot(e > 0.f);
      while (alive) {
        int lb = __ffsll((unsigned long long)alive) - 1;
        alive &= alive - 1;
        float w = __shfl(e, lb);
        int nn = __shfl(n, lb);
        u16x8 vvv = *(const u16x8*)(mvalT + ((size_t)b * N_ + nn) * DV_ + lane * 8);
        #pragma unroll
        for (int r = 0; r < 8; ++r) acc[r] += w * bf2f(vvv[r]);
      }
    }
    #pragma unroll
    for (int o = 32; o > 0; o >>= 1) lsum += __shfl_xor(lsum, o);
  }

  float inv = (lsum > 0.f) ? 1.0f / lsum : 0.0f;
  u16x8 ov;
  #pragma unroll
  for (int r = 0; r < 8; ++r) ov[r] = f2bf(acc[r] * inv);
  *(u16x8*)(outT + ((size_t)b * M_ + m) * DV_ + lane * 8) = ov;
}

// ---- transpose outT bf16 [B][M][Dv] -> out fp32 [B][Dv][M], applying qmask ----
__global__ __launch_bounds__(256)
void finalize_T(const unsigned short* __restrict__ outT, const int* __restrict__ qmask,
                float* __restrict__ out) {
  __shared__ float T[64][65];
  int b = blockIdx.z, dvt = blockIdx.y, mt = blockIdx.x;
  int lane = threadIdx.x & 63, ri = threadIdx.x >> 6;
  #pragma unroll
  for (int k = 0; k < 16; ++k) {
    int ml = ri * 16 + k;
    int m = mt * 64 + ml;
    bool act = (qmask[b * M_ + m] != 0);
    T[ml][lane] = act ? bf2f(outT[((size_t)b * M_ + m) * DV_ + dvt * 64 + lane]) : 0.f;
  }
  __syncthreads();
  #pragma unroll
  for (int k = 0; k < 16; ++k) {
    int dvl = ri * 16 + k;
    out[((size_t)b * DV_ + dvt * 64 + dvl) * M_ + mt * 64 + lane] = T[lane][dvl];
  }
}

extern "C" void kernel_launch(void* const* d_in, const int* in_sizes, int n_in,
                              void* d_out, int out_size, void* d_ws, size_t ws_size,
                              hipStream_t stream) {
  const float* qkey  = (const float*)d_in[0];
  const int*   qmask = (const int*)d_in[1];
  const float* mkey  = (const float*)d_in[2];
  const float* mval  = (const float*)d_in[3];
  const int*   mmask = (const int*)d_in[4];
  float* out = (float*)d_out;

  uint8_t* w = (uint8_t*)d_ws;
  unsigned*           bcnt   = (unsigned*)(w + 0);          // B*M u32, padded to 102400
  int*                qcnt   = (int*)(w + 102400);
  int*                qlist  = (int*)(w + 102528);          // B*M -> ends 202880
  unsigned long long* mmbits = (unsigned long long*)(w + 202880);   // 8*98 u64 -> 209152
  unsigned*           bucket = (unsigned*)(w + 209152);     // B*M*128 u32 -> 13054208
  float*              qkeyT  = (float*)(w + 13054208);      // B*M*128 f32 (x40)
  float*              mkeyT  = (float*)(w + 25899264);      // B*N*128 f32
  unsigned short*     mkb    = (unsigned short*)(w + 51589376); // B*N*128 bf16
  unsigned short*     outTb  = (unsigned short*)(w + 64434432); // B*M*512 bf16
  unsigned short*     mvalT  = (unsigned short*)(w + 90124544); // B*N*512 bf16
  // end: 141,504,768 bytes (<= previously proven-available workspace)

  prep_kernel<<<8665, 256, 0, stream>>>(qkey, qmask, mkey, mval, mmask,
                                        qkeyT, mkeyT, mkb, mvalT,
                                        qlist, qcnt, bcnt, mmbits);

  score_mfma<<<B_ * MT128_ * NSEG_, 256, 0, stream>>>(
      qkeyT, mkb, qlist, qcnt, mmbits, bcnt, bucket);

  pv_exact<<<dim3(M_ / 4, B_), 256, 0, stream>>>(
      qkeyT, mkeyT, mvalT, qlist, qcnt, mmask, bcnt, bucket, outTb);

  finalize_T<<<dim3(M_ / 64, DV_ / 64, B_), 256, 0, stream>>>(outTb, qmask, out);
}

// Round 7
// 205.113 us; speedup vs baseline: 1.1531x; 1.1531x over previous
//
#include <hip/hip_runtime.h>
#include <stdint.h>

#define B_    8
#define DK_   128
#define DV_   512
#define M_    3136      // H*W
#define N_    6272      // T*H*W
#define MT128_ 25       // ceil(3136/128)
#define NSEG_ 8
#define NTILES_ 98      // N_/64 dense
#define TH_   30.0f
#define MARGIN_ 36.0f
#define BKT_  64

typedef short bf16x8 __attribute__((ext_vector_type(8)));
typedef float f32x16 __attribute__((ext_vector_type(16)));
typedef unsigned short u16x8 __attribute__((ext_vector_type(8)));

__device__ __forceinline__ unsigned short f2bf(float x) {
  unsigned u = __float_as_uint(x);
  return (unsigned short)((u + 0x7fffu + ((u >> 16) & 1u)) >> 16);
}
__device__ __forceinline__ float bf2f(unsigned short h) {
  return __uint_as_float(((unsigned)h) << 16);
}

// ---- fused prep: vectorized transposes + q-scan + bcnt zero ----
// grid: [0,784) qkeyT+qkb; [784,2352) mkeyT+mkb(mask-zeroed); [2352,8624) mvalT;
//       [8624,8632) q scan; [8632,8657) zero bcnt
__global__ __launch_bounds__(256)
void prep_kernel(const float* __restrict__ qkey, const int* __restrict__ qmask,
                 const float* __restrict__ mkey, const float* __restrict__ mval,
                 const int* __restrict__ mmask,
                 float* __restrict__ qkeyT, unsigned short* __restrict__ qkb,
                 float* __restrict__ mkeyT, unsigned short* __restrict__ mkb,
                 unsigned short* __restrict__ mvalT,
                 int* __restrict__ qlist, int* __restrict__ qcnt,
                 unsigned* __restrict__ bcnt_z) {
  __shared__ float T[64][65];
  int r = blockIdx.x;
  int tid = threadIdx.x;
  int r16 = tid >> 4, c4 = (tid & 15) << 2;
  if (r < 784) {                       // qkey [B][128][M] -> fp32+bf16 [B][M][128], x40
    int xt = r % 49, dt = (r / 49) & 1, b = r / 98;
    const float* src = qkey + ((size_t)b * DK_ + dt * 64) * M_ + xt * 64;
    #pragma unroll
    for (int i = 0; i < 4; ++i) {
      int row = i * 16 + r16;
      float4 v = *(const float4*)&src[(size_t)row * M_ + c4];
      T[row][c4] = v.x; T[row][c4 + 1] = v.y; T[row][c4 + 2] = v.z; T[row][c4 + 3] = v.w;
    }
    __syncthreads();
    #pragma unroll
    for (int i = 0; i < 4; ++i) {
      int xl = i * 16 + r16;
      float4 v = make_float4(40.f * T[c4][xl], 40.f * T[c4 + 1][xl],
                             40.f * T[c4 + 2][xl], 40.f * T[c4 + 3][xl]);
      size_t idx = ((size_t)b * M_ + xt * 64 + xl) * DK_ + dt * 64 + c4;
      *(float4*)&qkeyT[idx] = v;
      ushort4 h;
      h.x = f2bf(v.x); h.y = f2bf(v.y); h.z = f2bf(v.z); h.w = f2bf(v.w);
      *(ushort4*)&qkb[idx] = h;
    }
  } else if (r < 2352) {               // mkey -> fp32 T (exact) + bf16 T (mask-zeroed)
    int r2 = r - 784;
    int xt = r2 % 98, dt = (r2 / 98) & 1, b = r2 / 196;
    const float* src = mkey + ((size_t)b * DK_ + dt * 64) * N_ + xt * 64;
    #pragma unroll
    for (int i = 0; i < 4; ++i) {
      int row = i * 16 + r16;
      float4 v = *(const float4*)&src[(size_t)row * N_ + c4];
      T[row][c4] = v.x; T[row][c4 + 1] = v.y; T[row][c4 + 2] = v.z; T[row][c4 + 3] = v.w;
    }
    __syncthreads();
    #pragma unroll
    for (int i = 0; i < 4; ++i) {
      int xl = i * 16 + r16;
      int n = xt * 64 + xl;
      bool act = (mmask[b * N_ + n] != 0);
      float4 v = make_float4(T[c4][xl], T[c4 + 1][xl], T[c4 + 2][xl], T[c4 + 3][xl]);
      size_t idx = ((size_t)b * N_ + n) * DK_ + dt * 64 + c4;
      *(float4*)&mkeyT[idx] = v;
      ushort4 h;
      if (act) { h.x = f2bf(v.x); h.y = f2bf(v.y); h.z = f2bf(v.z); h.w = f2bf(v.w); }
      else     { h.x = 0; h.y = 0; h.z = 0; h.w = 0; }
      *(ushort4*)&mkb[idx] = h;
    }
  } else if (r < 8624) {               // mval -> bf16 [B][N][512]
    int r3 = r - 2352;
    int nt = r3 % 98, dvt = (r3 / 98) & 7, b = r3 / 784;
    const float* src = mval + ((size_t)b * DV_ + dvt * 64) * N_ + nt * 64;
    #pragma unroll
    for (int i = 0; i < 4; ++i) {
      int row = i * 16 + r16;
      float4 v = *(const float4*)&src[(size_t)row * N_ + c4];
      T[row][c4] = v.x; T[row][c4 + 1] = v.y; T[row][c4 + 2] = v.z; T[row][c4 + 3] = v.w;
    }
    __syncthreads();
    #pragma unroll
    for (int i = 0; i < 4; ++i) {
      int xl = i * 16 + r16;
      ushort4 h;
      h.x = f2bf(T[c4][xl]); h.y = f2bf(T[c4 + 1][xl]);
      h.z = f2bf(T[c4 + 2][xl]); h.w = f2bf(T[c4 + 3][xl]);
      *(ushort4*)&mvalT[((size_t)b * N_ + nt * 64 + xl) * DV_ + dvt * 64 + c4] = h;
    }
  } else if (r < 8632) {               // q-mask compaction
    int b = r - 8624;
    __shared__ int wsum[4];
    __shared__ int cbase;
    int lane = tid & 63, wv = tid >> 6;
    if (tid == 0) cbase = 0;
    __syncthreads();
    for (int base = 0; base < M_; base += 256) {
      int i = base + tid;
      int flag = (i < M_) ? (qmask[b * M_ + i] != 0) : 0;
      unsigned long long bal = __ballot(flag);
      int prefix = __popcll(bal & ((1ull << lane) - 1ull));
      if (lane == 0) wsum[wv] = __popcll(bal);
      __syncthreads();
      int woff = 0;
      for (int t = 0; t < wv; ++t) woff += wsum[t];
      int total = wsum[0] + wsum[1] + wsum[2] + wsum[3];
      if (flag) qlist[b * M_ + cbase + woff + prefix] = i;
      __syncthreads();
      if (tid == 0) cbase += total;
      __syncthreads();
    }
    if (tid == 0) qcnt[b] = cbase;
  } else {                             // zero bcnt (25 x 4096B padded region)
    unsigned* p = bcnt_z + (size_t)(r - 8632) * 1024;
    for (int i = tid; i < 1024; i += 256) p[i] = 0u;
  }
}

// ---- bf16-MFMA score: masked rows pre-zeroed, cheap epilogue w/ skip guard ----
__global__ __launch_bounds__(256, 4)
void score_mfma(const unsigned short* __restrict__ qkb, const unsigned short* __restrict__ mkb,
                const int* __restrict__ qlist, const int* __restrict__ qcnt,
                unsigned* __restrict__ bcnt, unsigned* __restrict__ bucket) {
  int bid = blockIdx.x;
  int seg = bid & (NSEG_ - 1);
  int t   = bid >> 3;
  int mt  = t % MT128_;
  int b   = t / MT128_;
  int mc = qcnt[b];
  if (mt * 128 >= mc) return;
  int t0 = (NTILES_ * seg) / NSEG_;
  int t1 = (NTILES_ * (seg + 1)) / NSEG_;

  __shared__ unsigned short Ks[2][64 * 128];  // chunk-major: c*1024B + row*16B

  int tid = threadIdx.x;
  int lane = tid & 63, wv = tid >> 6;
  int l31 = lane & 31, lhi = lane >> 5;
  int mrow = wv * 32 + l31;

  // Q fragments from pre-packed bf16 (x40 folded)
  int cm = mt * 128 + mrow;
  int col = (cm < mc) ? qlist[b * M_ + cm] : qlist[b * M_];
  int mo  = (cm < mc) ? col : -1;
  const unsigned short* qrow = qkb + ((size_t)b * M_ + col) * DK_;
  bf16x8 qf[8];
  #pragma unroll
  for (int kc = 0; kc < 8; ++kc)
    qf[kc] = *(const bf16x8*)(qrow + (kc * 2 + lhi) * 8);

  const unsigned short* mkb_b = mkb + (size_t)b * N_ * DK_;

  // prologue: stage tile t0 into buf 0 (linear DMA dest)
  {
    int nbase = t0 << 6;
    char* kd = (char*)&Ks[0][0];
    #pragma unroll
    for (int i = 0; i < 4; ++i) {
      int c = wv * 4 + i;
      const unsigned short* src = mkb_b + ((size_t)(nbase + lane)) * DK_ + c * 8;
      __builtin_amdgcn_global_load_lds(
          (const __attribute__((address_space(1))) unsigned*)src,
          (__attribute__((address_space(3))) unsigned*)(kd + c * 1024), 16, 0, 0);
    }
  }
  asm volatile("s_waitcnt vmcnt(0)" ::: "memory");
  __syncthreads();

  float runmax = -3.0e38f;

  for (int tt = t0; tt < t1; ++tt) {
    int cur = (tt - t0) & 1;
    int nbase = tt << 6;
    // prefetch next tile
    if (tt + 1 < t1) {
      int nb2 = (tt + 1) << 6;
      char* kd = (char*)&Ks[cur ^ 1][0];
      #pragma unroll
      for (int i = 0; i < 4; ++i) {
        int c = wv * 4 + i;
        const unsigned short* src = mkb_b + ((size_t)(nb2 + lane)) * DK_ + c * 8;
        __builtin_amdgcn_global_load_lds(
            (const __attribute__((address_space(1))) unsigned*)src,
            (__attribute__((address_space(3))) unsigned*)(kd + c * 1024), 16, 0, 0);
      }
    }

    const char* kb = (const char*)&Ks[cur][0];
    f32x16 acc0, acc1;
    #pragma unroll
    for (int r = 0; r < 16; ++r) { acc0[r] = 0.f; acc1[r] = 0.f; }
    #pragma unroll
    for (int kc = 0; kc < 8; ++kc) {
      int c = kc * 2 + lhi;
      bf16x8 a0 = *(const bf16x8*)(kb + c * 1024 + l31 * 16);
      bf16x8 a1 = *(const bf16x8*)(kb + c * 1024 + (32 + l31) * 16);
      acc0 = __builtin_amdgcn_mfma_f32_32x32x16_bf16(a0, qf[kc], acc0, 0, 0, 0);
      acc1 = __builtin_amdgcn_mfma_f32_32x32x16_bf16(a1, qf[kc], acc1, 0, 0, 0);
    }

    // running column max (masked rows contribute exactly 0, never dominate)
    float cmxl = fmaxf(acc0[0], acc1[0]);
    #pragma unroll
    for (int r = 1; r < 16; ++r) cmxl = fmaxf(cmxl, fmaxf(acc0[r], acc1[r]));
    float cmx = fmaxf(cmxl, __shfl_xor(cmxl, 32));
    runmax = fmaxf(runmax, cmx);

    // skip-guard: only scan when this lane could possibly append
    if (mo >= 0 && cmxl >= runmax - MARGIN_) {
      float thr = runmax - MARGIN_;
      #pragma unroll
      for (int r = 0; r < 16; ++r) {
        const int pos = (r & 3) + ((r >> 2) << 3);
        if (acc0[r] >= thr) {
          unsigned slot = atomicAdd(&bcnt[b * M_ + mo], 1u);
          if (slot < (unsigned)BKT_)
            bucket[(((size_t)(b * M_ + mo)) << 6) + slot] =
                (unsigned)(nbase + pos + (lhi << 2));
        }
        if (acc1[r] >= thr) {
          unsigned slot = atomicAdd(&bcnt[b * M_ + mo], 1u);
          if (slot < (unsigned)BKT_)
            bucket[(((size_t)(b * M_ + mo)) << 6) + slot] =
                (unsigned)(nbase + 32 + pos + (lhi << 2));
        }
      }
    }

    asm volatile("s_waitcnt vmcnt(0)" ::: "memory");
    __syncthreads();
  }
}

__device__ __forceinline__ float dot128(const float* __restrict__ q,
                                        const float* __restrict__ k) {
  float s = 0.f;
  #pragma unroll 8
  for (int i = 0; i < DK_; i += 4) {
    float4 a = *(const float4*)&q[i];
    float4 bb = *(const float4*)&k[i];
    s += a.x * bb.x + a.y * bb.y + a.z * bb.z + a.w * bb.w;
  }
  return s;
}

// ---- PV: one wave per active column; exact fp32 rescore + mmask filter ----
__global__ __launch_bounds__(256)
void pv_exact(const float* __restrict__ qkeyT, const float* __restrict__ mkeyT,
              const unsigned short* __restrict__ mvalT,
              const int* __restrict__ qlist, const int* __restrict__ qcnt,
              const int* __restrict__ mmask,
              const unsigned* __restrict__ bcnt, const unsigned* __restrict__ bucket,
              unsigned short* __restrict__ outT) {
  int b = blockIdx.y;
  int wv = threadIdx.x >> 6, lane = threadIdx.x & 63;
  int c = blockIdx.x * 4 + wv;
  if (c >= qcnt[b]) return;
  int m = qlist[b * M_ + c];
  unsigned cnt = bcnt[b * M_ + m];
  const float* qrow = qkeyT + ((size_t)b * M_ + m) * DK_;
  float acc[8] = {0.f, 0.f, 0.f, 0.f, 0.f, 0.f, 0.f, 0.f};
  float lsum = 0.f;

  if (cnt <= (unsigned)BKT_) {
    int n = -1;
    if (lane < (int)cnt) n = (int)bucket[(((size_t)(b * M_ + m)) << 6) + lane];
    if (n >= 0 && mmask[b * N_ + n] == 0) n = -1;   // drop masked strays
    float sv = -3.0e38f;
    if (n >= 0) sv = dot128(qrow, mkeyT + ((size_t)b * N_ + n) * DK_);
    float mx = sv;
    #pragma unroll
    for (int o = 32; o > 0; o >>= 1) mx = fmaxf(mx, __shfl_xor(mx, o));
    float e = (n >= 0 && sv >= mx - TH_) ? expf(sv - mx) : 0.f;
    lsum = e;
    #pragma unroll
    for (int o = 32; o > 0; o >>= 1) lsum += __shfl_xor(lsum, o);
    unsigned long long alive = __ballot(e > 0.f);
    while (alive) {
      int lb = __ffsll((unsigned long long)alive) - 1;
      alive &= alive - 1;
      float w = __shfl(e, lb);
      int nn = __shfl(n, lb);
      u16x8 vvv = *(const u16x8*)(mvalT + ((size_t)b * N_ + nn) * DV_ + lane * 8);
      #pragma unroll
      for (int r = 0; r < 8; ++r) acc[r] += w * bf2f(vvv[r]);
    }
  } else {
    // overflow fallback (statistically unreachable): exact dense two-pass
    float mx = -3.0e38f;
    for (int base = 0; base < N_; base += 64) {
      int n = base + lane;
      float sv = -3.0e38f;
      if (mmask[b * N_ + n] != 0)
        sv = dot128(qrow, mkeyT + ((size_t)b * N_ + n) * DK_);
      mx = fmaxf(mx, sv);
    }
    #pragma unroll
    for (int o = 32; o > 0; o >>= 1) mx = fmaxf(mx, __shfl_xor(mx, o));
    for (int base = 0; base < N_; base += 64) {
      int n = base + lane;
      bool act = (mmask[b * N_ + n] != 0);
      float sv = -3.0e38f;
      if (act) sv = dot128(qrow, mkeyT + ((size_t)b * N_ + n) * DK_);
      float e = (act && sv >= mx - TH_) ? expf(sv - mx) : 0.f;
      lsum += e;
      unsigned long long alive = __ballot(e > 0.f);
      while (alive) {
        int lb = __ffsll((unsigned long long)alive) - 1;
        alive &= alive - 1;
        float w = __shfl(e, lb);
        int nn = __shfl(n, lb);
        u16x8 vvv = *(const u16x8*)(mvalT + ((size_t)b * N_ + nn) * DV_ + lane * 8);
        #pragma unroll
        for (int r = 0; r < 8; ++r) acc[r] += w * bf2f(vvv[r]);
      }
    }
    #pragma unroll
    for (int o = 32; o > 0; o >>= 1) lsum += __shfl_xor(lsum, o);
  }

  float inv = (lsum > 0.f) ? 1.0f / lsum : 0.0f;
  u16x8 ov;
  #pragma unroll
  for (int r = 0; r < 8; ++r) ov[r] = f2bf(acc[r] * inv);
  *(u16x8*)(outT + ((size_t)b * M_ + m) * DV_ + lane * 8) = ov;
}

// ---- transpose outT bf16 [B][M][Dv] -> out fp32 [B][Dv][M], applying qmask ----
__global__ __launch_bounds__(256)
void finalize_T(const unsigned short* __restrict__ outT, const int* __restrict__ qmask,
                float* __restrict__ out) {
  __shared__ float T[64][65];
  int b = blockIdx.z, dvt = blockIdx.y, mt = blockIdx.x;
  int lane = threadIdx.x & 63, ri = threadIdx.x >> 6;
  #pragma unroll
  for (int k = 0; k < 16; ++k) {
    int ml = ri * 16 + k;
    int m = mt * 64 + ml;
    bool act = (qmask[b * M_ + m] != 0);
    T[ml][lane] = act ? bf2f(outT[((size_t)b * M_ + m) * DV_ + dvt * 64 + lane]) : 0.f;
  }
  __syncthreads();
  #pragma unroll
  for (int k = 0; k < 16; ++k) {
    int dvl = ri * 16 + k;
    out[((size_t)b * DV_ + dvt * 64 + dvl) * M_ + mt * 64 + lane] = T[lane][dvl];
  }
}

extern "C" void kernel_launch(void* const* d_in, const int* in_sizes, int n_in,
                              void* d_out, int out_size, void* d_ws, size_t ws_size,
                              hipStream_t stream) {
  const float* qkey  = (const float*)d_in[0];
  const int*   qmask = (const int*)d_in[1];
  const float* mkey  = (const float*)d_in[2];
  const float* mval  = (const float*)d_in[3];
  const int*   mmask = (const int*)d_in[4];
  float* out = (float*)d_out;

  uint8_t* w = (uint8_t*)d_ws;
  unsigned*       bcnt   = (unsigned*)(w + 0);              // B*M u32 (pad to 102400)
  int*            qcnt   = (int*)(w + 102400);
  int*            qlist  = (int*)(w + 102528);              // B*M -> 202880
  unsigned*       bucket = (unsigned*)(w + 202880);         // B*M*64 -> 6625408
  float*          qkeyT  = (float*)(w + 6625408);           // B*M*128 f32 (x40)
  float*          mkeyT  = (float*)(w + 19470464);          // B*N*128 f32 (exact)
  unsigned short* qkb    = (unsigned short*)(w + 45160576); // B*M*128 bf16 (x40)
  unsigned short* mkb    = (unsigned short*)(w + 51583104); // B*N*128 bf16 (mask-zeroed)
  unsigned short* outTb  = (unsigned short*)(w + 64428160); // B*M*512 bf16
  unsigned short* mvalT  = (unsigned short*)(w + 90118272); // B*N*512 bf16
  // end: 141,498,496 bytes (<= previously proven-available workspace)

  prep_kernel<<<8657, 256, 0, stream>>>(qkey, qmask, mkey, mval, mmask,
                                        qkeyT, qkb, mkeyT, mkb, mvalT,
                                        qlist, qcnt, bcnt);

  score_mfma<<<B_ * MT128_ * NSEG_, 256, 0, stream>>>(
      qkb, mkb, qlist, qcnt, bcnt, bucket);

  pv_exact<<<dim3(M_ / 4, B_), 256, 0, stream>>>(
      qkeyT, mkeyT, mvalT, qlist, qcnt, mmask, bcnt, bucket, outTb);

  finalize_T<<<dim3(M_ / 64, DV_ / 64, B_), 256, 0, stream>>>(outTb, qmask, out);
}